// Round 6
// baseline (618.337 us; speedup 1.0000x reference)
//
#include <hip/hip_runtime.h>
#include <hip/hip_cooperative_groups.h>

namespace cg = cooperative_groups;

// DBASolver: B=16, N=196608, C=2.
// R7: single fused cooperative kernel.
//   Phase A: per-thread loop over 12 pairs: accumulate H_eff(21)+g_eff(6)
//            AND keep per-point depth coefficients c7={hii[0..5],gdinv} in
//            REGISTERS (statically indexed via full unroll).
//   sync -> 16 threads do the 6x6 Gauss-Jordan solves -> sync
//   Phase C: depth = gdinv - hii.dp straight from registers. ZERO re-read.
// Traffic: 226.5 MB read + 12.6 MB write (was ~440 MB across 2 passes).
// Evidence base: delivered read BW pins at ~2.46 TB/s regardless of
// coalescing (R2), prefetch (R4: compiler deleted it, VGPR=64), nt hints,
// occupancy 8-24 w/CU. Writes compete for the same pipeline (R5: +100MB
// writes in pass1 ate pass3's savings). Only lever: move fewer bytes.
// Geometry: 512 blocks x 256 thr, __launch_bounds__(256,2) -> 2 blocks/CU
// co-resident (VGPR cap 256; c7 regs 168 + A/g 27 + transients ~= 245).
// 32 blocks/batch -> 8192 thr/batch -> 98304/8192 = 12 pairs/thread exact.
// Fallback 3-kernel path for non-matching shapes or coop-launch failure.

using f4 = __attribute__((ext_vector_type(4))) float;
using f2 = __attribute__((ext_vector_type(2))) float;

constexpr int NACC = 27;   // 21 upper-tri H + 6 g
constexpr int CHUNKS = 12; // pairs per thread in fused kernel

// Per-point contribution; exports c7 = {hii[0..5], gdinv}:
// depth = gdinv - hii.dp (exact same arithmetic pass 3 needs).
__device__ __forceinline__ void accum_point(
    const float ja[6], const float jb[6],
    float r0, float r1, float conf, float nlam, float jd0, float jd1,
    float lam, float* __restrict__ A, float* __restrict__ g,
    float* __restrict__ c7)
{
    float h[6], gp[6];
#pragma unroll
    for (int i = 0; i < 6; ++i) {
        h[i]  = conf * (ja[i] * jd0 + jb[i] * jd1);   // H_pd[b,n,i]
        gp[i] = conf * (ja[i] * r0 + jb[i] * r1);     // g_p contribution
    }
    const float hdd = conf * (jd0 * jd0 + jd1 * jd1);
    const float inv = 1.0f / fmaxf(hdd + lam + nlam, 1e-4f);
    const float gd  = conf * (jd0 * r0 + jd1 * r1);
    const float gdinv = gd * inv;
    c7[6] = gdinv;
    int idx = 0;
#pragma unroll
    for (int i = 0; i < 6; ++i) {
        const float hii = h[i] * inv;
        c7[i] = hii;
#pragma unroll
        for (int j = i; j < 6; ++j) {
            A[idx] += conf * (ja[i] * ja[j] + jb[i] * jb[j]) - hii * h[j];
            ++idx;
        }
        g[i] += gp[i] - h[i] * gdinv;
    }
}

__device__ __forceinline__ void solve6(const float* __restrict__ a, float lam,
                                       float* __restrict__ pose,
                                       float* __restrict__ dp)
{
    float M[6][7];
    int idx = 0;
#pragma unroll
    for (int i = 0; i < 6; ++i) {
#pragma unroll
        for (int j = i; j < 6; ++j) {
            const float t = a[idx++];
            M[i][j] = t;
            M[j][i] = t;
        }
    }
#pragma unroll
    for (int i = 0; i < 6; ++i) M[i][6] = a[21 + i];
#pragma unroll
    for (int i = 0; i < 6; ++i) M[i][i] += lam + 0.011f;  // lmbda + 0.011

    // Gauss-Jordan, no pivoting (strongly diagonally dominant SPD)
#pragma unroll
    for (int k = 0; k < 6; ++k) {
        const float piv = 1.0f / M[k][k];
#pragma unroll
        for (int j = 0; j < 7; ++j) M[k][j] *= piv;
#pragma unroll
        for (int i = 0; i < 6; ++i) {
            if (i == k) continue;
            const float f = M[i][k];
#pragma unroll
            for (int j = 0; j < 7; ++j) M[i][j] -= f * M[k][j];
        }
    }
#pragma unroll
    for (int i = 0; i < 6; ++i) {
        const float x = M[i][6];
        dp[i] = x;                                   // UNCLIPPED for depth
        pose[i] = fminf(fmaxf(x, -2.0f), 2.0f);
    }
}

// ---------------- fused cooperative kernel (exact shape only) --------------
__global__ __launch_bounds__(256, 2) void dba_fused(
    const float* __restrict__ r, const float* __restrict__ w,
    const float* __restrict__ J_p, const float* __restrict__ J_d,
    const float* __restrict__ lmbda, float* __restrict__ acc,
    float* __restrict__ dp_ws, float* __restrict__ pose_out,
    float* __restrict__ depth_out, int N)
{
    const int b  = blockIdx.x >> 5;        // 32 blocks per batch
    const int bb = blockIdx.x & 31;
    const int tid_b = (bb << 8) + threadIdx.x;   // 0..8191 within batch
    const float lam = lmbda[b];

    const size_t basePt = (size_t)b * (size_t)N;
    const f4* __restrict__ r4  = (const f4*)r   + (basePt >> 1);
    const f4* __restrict__ w4  = (const f4*)w   + (basePt >> 1);
    const f4* __restrict__ jd4 = (const f4*)J_d + (basePt >> 1);
    const f4* __restrict__ jp4 = (const f4*)J_p + basePt * 3;
    f2* __restrict__ out2 = (f2*)depth_out + (basePt >> 1);

    float A[21];
    float g[6];
#pragma unroll
    for (int i = 0; i < 21; ++i) A[i] = 0.f;
#pragma unroll
    for (int i = 0; i < 6; ++i) g[i] = 0.f;

    float ca[CHUNKS][7];   // point A coefficients, statically indexed
    float cb[CHUNKS][7];   // point B coefficients

    // ---- Phase A: reduction + coefficient capture ----
#pragma unroll
    for (int it = 0; it < CHUNKS; ++it) {
        const int pr = tid_b + it * 8192;
        const f4 rv = r4[pr];
        const f4 wv = w4[pr];
        const f4 jd = jd4[pr];
        const f4* jp = jp4 + (size_t)pr * 6;
        const f4 q0 = jp[0];
        const f4 q1 = jp[1];
        const f4 q2 = jp[2];
        const f4 q3 = jp[3];
        const f4 q4 = jp[4];
        const f4 q5 = jp[5];
        {
            const float ja[6] = {q0[0], q0[1], q0[2], q0[3], q1[0], q1[1]};
            const float jb[6] = {q1[2], q1[3], q2[0], q2[1], q2[2], q2[3]};
            accum_point(ja, jb, rv[0], rv[1], wv[0], wv[1], jd[0], jd[1],
                        lam, A, g, ca[it]);
        }
        {
            const float ja[6] = {q3[0], q3[1], q3[2], q3[3], q4[0], q4[1]};
            const float jb[6] = {q4[2], q4[3], q5[0], q5[1], q5[2], q5[3]};
            accum_point(ja, jb, rv[2], rv[3], wv[2], wv[3], jd[2], jd[3],
                        lam, A, g, cb[it]);
        }
    }

    // ---- block reduction -> device atomics ----
    {
        float v[NACC];
#pragma unroll
        for (int i = 0; i < 21; ++i) v[i] = A[i];
#pragma unroll
        for (int i = 0; i < 6; ++i) v[21 + i] = g[i];
#pragma unroll
        for (int off = 32; off > 0; off >>= 1) {
#pragma unroll
            for (int i = 0; i < NACC; ++i) v[i] += __shfl_down(v[i], off, 64);
        }
        __shared__ float sred[4][NACC];
        const int wave = threadIdx.x >> 6;
        const int lane = threadIdx.x & 63;
        if (lane == 0) {
#pragma unroll
            for (int i = 0; i < NACC; ++i) sred[wave][i] = v[i];
        }
        __syncthreads();
        if (threadIdx.x < NACC) {
            const float s = sred[0][threadIdx.x] + sred[1][threadIdx.x] +
                            sred[2][threadIdx.x] + sred[3][threadIdx.x];
            atomicAdd(&acc[b * 32 + threadIdx.x], s);
        }
    }

    __threadfence();
    cg::this_grid().sync();

    // ---- solve: 16 threads (one block each) ----
    if (blockIdx.x < 16 && threadIdx.x == 0) {
        const int sb = blockIdx.x;
        solve6(acc + sb * 32, lmbda[sb], pose_out + sb * 6, dp_ws + sb * 6);
    }
    __threadfence();
    cg::this_grid().sync();

    // ---- Phase C: depth from registers ----
    float dp[6];
#pragma unroll
    for (int i = 0; i < 6; ++i) dp[i] = dp_ws[b * 6 + i];

#pragma unroll
    for (int it = 0; it < CHUNKS; ++it) {
        const int pr = tid_b + it * 8192;
        f2 o;
        o[0] = ca[it][6] - (ca[it][0] * dp[0] + ca[it][1] * dp[1] +
                            ca[it][2] * dp[2] + ca[it][3] * dp[3] +
                            ca[it][4] * dp[4] + ca[it][5] * dp[5]);
        o[1] = cb[it][6] - (cb[it][0] * dp[0] + cb[it][1] * dp[1] +
                            cb[it][2] * dp[2] + cb[it][3] * dp[3] +
                            cb[it][4] * dp[4] + cb[it][5] * dp[5]);
        out2[pr] = o;
    }
}

// ---------------- fallback 3-kernel path (generic shapes) -----------------
__global__ __launch_bounds__(256) void dba_reduce_fb(
    const float* __restrict__ r, const float* __restrict__ w,
    const float* __restrict__ J_p, const float* __restrict__ J_d,
    const float* __restrict__ lmbda, float* __restrict__ acc, int N)
{
    const int b = blockIdx.y;
    const float lam = lmbda[b];
    float A[21];
    float g[6];
#pragma unroll
    for (int i = 0; i < 21; ++i) A[i] = 0.f;
#pragma unroll
    for (int i = 0; i < 6; ++i) g[i] = 0.f;

    const size_t basePt = (size_t)b * (size_t)N;
    const int P = N >> 1;
    const f4* __restrict__ r4  = (const f4*)r   + (basePt >> 1);
    const f4* __restrict__ w4  = (const f4*)w   + (basePt >> 1);
    const f4* __restrict__ jd4 = (const f4*)J_d + (basePt >> 1);
    const f4* __restrict__ jp4 = (const f4*)J_p + basePt * 3;

    float c7a[7], c7b[7];
    for (int pr = blockIdx.x * blockDim.x + threadIdx.x; pr < P;
         pr += gridDim.x * blockDim.x) {
        const f4 rv = r4[pr];
        const f4 wv = w4[pr];
        const f4 jd = jd4[pr];
        const f4* jp = jp4 + (size_t)pr * 6;
        const f4 q0 = jp[0], q1 = jp[1], q2 = jp[2];
        const f4 q3 = jp[3], q4 = jp[4], q5 = jp[5];
        {
            const float ja[6] = {q0[0], q0[1], q0[2], q0[3], q1[0], q1[1]};
            const float jb[6] = {q1[2], q1[3], q2[0], q2[1], q2[2], q2[3]};
            accum_point(ja, jb, rv[0], rv[1], wv[0], wv[1], jd[0], jd[1],
                        lam, A, g, c7a);
        }
        {
            const float ja[6] = {q3[0], q3[1], q3[2], q3[3], q4[0], q4[1]};
            const float jb[6] = {q4[2], q4[3], q5[0], q5[1], q5[2], q5[3]};
            accum_point(ja, jb, rv[2], rv[3], wv[2], wv[3], jd[2], jd[3],
                        lam, A, g, c7b);
        }
    }

    float v[NACC];
#pragma unroll
    for (int i = 0; i < 21; ++i) v[i] = A[i];
#pragma unroll
    for (int i = 0; i < 6; ++i) v[21 + i] = g[i];
#pragma unroll
    for (int off = 32; off > 0; off >>= 1) {
#pragma unroll
        for (int i = 0; i < NACC; ++i) v[i] += __shfl_down(v[i], off, 64);
    }
    __shared__ float sred[4][NACC];
    const int wave = threadIdx.x >> 6;
    const int lane = threadIdx.x & 63;
    if (lane == 0) {
#pragma unroll
        for (int i = 0; i < NACC; ++i) sred[wave][i] = v[i];
    }
    __syncthreads();
    if (threadIdx.x < NACC) {
        const float s = sred[0][threadIdx.x] + sred[1][threadIdx.x] +
                        sred[2][threadIdx.x] + sred[3][threadIdx.x];
        atomicAdd(&acc[b * 32 + threadIdx.x], s);
    }
}

__global__ void dba_solve_fb(const float* __restrict__ acc,
                             const float* __restrict__ lmbda,
                             float* __restrict__ pose_out,
                             float* __restrict__ dp_ws, int B)
{
    const int b = blockIdx.x * blockDim.x + threadIdx.x;
    if (b >= B) return;
    solve6(acc + b * 32, lmbda[b], pose_out + b * 6, dp_ws + b * 6);
}

__global__ __launch_bounds__(256) void dba_depth_fb(
    const float* __restrict__ r, const float* __restrict__ w,
    const float* __restrict__ J_p, const float* __restrict__ J_d,
    const float* __restrict__ lmbda, const float* __restrict__ dp_ws,
    float* __restrict__ depth_out, int N)
{
    const int b = blockIdx.y;
    const float lam = lmbda[b];
    float dp[6];
#pragma unroll
    for (int i = 0; i < 6; ++i) dp[i] = dp_ws[b * 6 + i];

    const size_t basePt = (size_t)b * (size_t)N;
    const int P = N >> 1;
    const f4* __restrict__ r4  = (const f4*)r   + (basePt >> 1);
    const f4* __restrict__ w4  = (const f4*)w   + (basePt >> 1);
    const f4* __restrict__ jd4 = (const f4*)J_d + (basePt >> 1);
    const f4* __restrict__ jp4 = (const f4*)J_p + basePt * 3;
    f2* __restrict__ out2 = (f2*)depth_out + (basePt >> 1);

    for (int pr = blockIdx.x * blockDim.x + threadIdx.x; pr < P;
         pr += gridDim.x * blockDim.x) {
        const f4 rv = r4[pr];
        const f4 wv = w4[pr];
        const f4 jd = jd4[pr];
        const f4* jp = jp4 + (size_t)pr * 6;
        const f4 q0 = jp[0], q1 = jp[1], q2 = jp[2];
        const f4 q3 = jp[3], q4 = jp[4], q5 = jp[5];
        f2 o;
        {
            const float ja[6] = {q0[0], q0[1], q0[2], q0[3], q1[0], q1[1]};
            const float jb[6] = {q1[2], q1[3], q2[0], q2[1], q2[2], q2[3]};
            float v = 0.f;
#pragma unroll
            for (int i = 0; i < 6; ++i)
                v += (ja[i] * jd[0] + jb[i] * jd[1]) * dp[i];
            v *= wv[0];
            const float hdd = wv[0] * (jd[0] * jd[0] + jd[1] * jd[1]);
            const float inv = 1.0f / fmaxf(hdd + lam + wv[1], 1e-4f);
            const float gd  = wv[0] * (jd[0] * rv[0] + jd[1] * rv[1]);
            o[0] = inv * (gd - v);
        }
        {
            const float ja[6] = {q3[0], q3[1], q3[2], q3[3], q4[0], q4[1]};
            const float jb[6] = {q4[2], q4[3], q5[0], q5[1], q5[2], q5[3]};
            float v = 0.f;
#pragma unroll
            for (int i = 0; i < 6; ++i)
                v += (ja[i] * jd[2] + jb[i] * jd[3]) * dp[i];
            v *= wv[2];
            const float hdd = wv[2] * (jd[2] * jd[2] + jd[3] * jd[3]);
            const float inv = 1.0f / fmaxf(hdd + lam + wv[3], 1e-4f);
            const float gd  = wv[2] * (jd[2] * rv[2] + jd[3] * rv[3]);
            o[1] = inv * (gd - v);
        }
        out2[pr] = o;
    }
}

extern "C" void kernel_launch(void* const* d_in, const int* in_sizes, int n_in,
                              void* d_out, int out_size, void* d_ws, size_t ws_size,
                              hipStream_t stream)
{
    const float* r   = (const float*)d_in[0];
    const float* w   = (const float*)d_in[1];
    const float* J_p = (const float*)d_in[2];
    const float* J_d = (const float*)d_in[3];
    const float* lmb = (const float*)d_in[4];
    const int B = in_sizes[4];            // 16
    const int N = in_sizes[0] / (B * 2);  // 196608

    float* acc   = (float*)d_ws;           // B*32 floats
    float* dp_ws = (float*)d_ws + 512;     // B*6 floats
    float* out   = (float*)d_out;
    float* pose  = out;
    float* depth = out + B * 6;

    hipMemsetAsync(acc, 0, B * 32 * sizeof(float), stream);

    static int coop = -1;
    if (coop < 0) {
        int dev = 0, v = 0;
        hipGetDevice(&dev);
        hipDeviceGetAttribute(&v, hipDeviceAttributeCooperativeLaunch, dev);
        coop = v;
    }

    // fused path: exact geometry 512 blocks x 256 thr x 12 pairs/thread
    if (coop && B == 16 && N == 196608) {
        int n = N;
        void* args[] = {(void*)&r,   (void*)&w,     (void*)&J_p,
                        (void*)&J_d, (void*)&lmb,   (void*)&acc,
                        (void*)&dp_ws, (void*)&pose, (void*)&depth,
                        (void*)&n};
        hipError_t e = hipLaunchCooperativeKernel(
            (const void*)dba_fused, dim3(512), dim3(256), args, 0, stream);
        if (e == hipSuccess) return;
    }

    // fallback: 3-kernel path
    dim3 grid(192, B);
    dba_reduce_fb<<<grid, 256, 0, stream>>>(r, w, J_p, J_d, lmb, acc, N);
    dba_solve_fb<<<1, 64, 0, stream>>>(acc, lmb, pose, dp_ws, B);
    dba_depth_fb<<<grid, 256, 0, stream>>>(r, w, J_p, J_d, lmb, dp_ws,
                                           depth, N);
}

// Round 7
// 312.164 us; speedup vs baseline: 1.9808x; 1.9808x over previous
//
#include <hip/hip_runtime.h>

// DBASolver: B=16, N=196608, C=2.
// Structure (best known, R5): reduce(+c7 cache) -> 16x 6x6 solve -> slim depth.
// R7 fused-coop FAILED: compiler capped VGPR at 128, spilled 168-float c7 to
// scratch (WRITE 241 MB, VALU 3.4%, 421us). Register residency infeasible.
// Evidence: delivered read rate pins ~2.46-2.6 TB/s regardless of coalescing
// (R2), prefetch/nt (R4), occupancy. Byte-count is the only proven lever (R5).
// R8: (1) XCD-contiguous partitioning: xcd = blockid%8 owns a CONTIGUOUS 1/8
//     of each batch's range (was fine-grain interleaved across all 8 L2s ->
//     max fabric crossing). (2) c7 cache tight-packed 28 B/pt (88.1 MB, was
//     100.7). (3) nt input loads (don't evict c7 cache from LLC); cache
//     stores write-back (want LLC hits in depth pass). (4) dropped the LDS
//     transpose (R2 proved coalescing-neutral; simpler, no fences).

using f4 = __attribute__((ext_vector_type(4))) float;
using f2 = __attribute__((ext_vector_type(2))) float;

__device__ __forceinline__ f4 ntload4(const f4* p) {
    return __builtin_nontemporal_load(p);
}

constexpr int NACC = 27;  // 21 upper-tri H + 6 g

// Per-point contribution; exports c7 = {hii[0..5], gdinv}:
// depth = gdinv - hii.dp (identical arithmetic to what pass 3 needs).
__device__ __forceinline__ void accum_point(
    const float ja[6], const float jb[6],
    float r0, float r1, float conf, float nlam, float jd0, float jd1,
    float lam, float* __restrict__ A, float* __restrict__ g,
    float* __restrict__ c7)
{
    float h[6], gp[6];
#pragma unroll
    for (int i = 0; i < 6; ++i) {
        h[i]  = conf * (ja[i] * jd0 + jb[i] * jd1);   // H_pd[b,n,i]
        gp[i] = conf * (ja[i] * r0 + jb[i] * r1);     // g_p contribution
    }
    const float hdd = conf * (jd0 * jd0 + jd1 * jd1);
    const float inv = 1.0f / fmaxf(hdd + lam + nlam, 1e-4f);
    const float gd  = conf * (jd0 * r0 + jd1 * r1);
    const float gdinv = gd * inv;
    c7[6] = gdinv;
    int idx = 0;
#pragma unroll
    for (int i = 0; i < 6; ++i) {
        const float hii = h[i] * inv;
        c7[i] = hii;
#pragma unroll
        for (int j = i; j < 6; ++j) {
            A[idx] += conf * (ja[i] * ja[j] + jb[i] * jb[j]) - hii * h[j];
            ++idx;
        }
        g[i] += gp[i] - h[i] * gdinv;
    }
}

__device__ __forceinline__ void solve6(const float* __restrict__ a, float lam,
                                       float* __restrict__ pose,
                                       float* __restrict__ dp)
{
    float M[6][7];
    int idx = 0;
#pragma unroll
    for (int i = 0; i < 6; ++i) {
#pragma unroll
        for (int j = i; j < 6; ++j) {
            const float t = a[idx++];
            M[i][j] = t;
            M[j][i] = t;
        }
    }
#pragma unroll
    for (int i = 0; i < 6; ++i) M[i][6] = a[21 + i];
#pragma unroll
    for (int i = 0; i < 6; ++i) M[i][i] += lam + 0.011f;
    // Gauss-Jordan, no pivoting (strongly diagonally dominant SPD)
#pragma unroll
    for (int k = 0; k < 6; ++k) {
        const float piv = 1.0f / M[k][k];
#pragma unroll
        for (int j = 0; j < 7; ++j) M[k][j] *= piv;
#pragma unroll
        for (int i = 0; i < 6; ++i) {
            if (i == k) continue;
            const float f = M[i][k];
#pragma unroll
            for (int j = 0; j < 7; ++j) M[i][j] -= f * M[k][j];
        }
    }
#pragma unroll
    for (int i = 0; i < 6; ++i) {
        const float x = M[i][6];
        dp[i] = x;                                   // UNCLIPPED for depth
        pose[i] = fminf(fmaxf(x, -2.0f), 2.0f);
    }
}

// ---------------- XCD-contiguous reduce (exact shape) ----------------------
// grid (64, B): 1024 blocks = 4/CU. Each XCD owns chunks
// [xcd*192, (xcd+1)*192) of the batch (chunk = 64 pairs); its 8 blocks x 4
// waves take 6 contiguous chunks each. All reads within an XCD hit a
// contiguous ~28 MB/8 slab of each input array.
__global__ __launch_bounds__(256) void dba_reduce_swz(
    const float* __restrict__ r, const float* __restrict__ w,
    const float* __restrict__ J_p, const float* __restrict__ J_d,
    const float* __restrict__ lmbda, float* __restrict__ acc,
    float* __restrict__ cA, float* __restrict__ cB, float* __restrict__ cC,
    int N)
{
    const int b = blockIdx.y;
    const float lam = lmbda[b];
    const int lane = threadIdx.x & 63;
    const int wave = threadIdx.x >> 6;

    const size_t basePt = (size_t)b * (size_t)N;
    const int P = N >> 1;
    const f4* __restrict__ r4  = (const f4*)r   + (basePt >> 1);
    const f4* __restrict__ w4  = (const f4*)w   + (basePt >> 1);
    const f4* __restrict__ jd4 = (const f4*)J_d + (basePt >> 1);
    const f4* __restrict__ jp4 = (const f4*)J_p + basePt * 3;
    f4* __restrict__ cA4 = (f4*)cA + basePt;            // 1 f4 per point
    f4* __restrict__ cB4 = (f4*)cB + (basePt >> 1);     // 1 f4 per pair
    f2* __restrict__ cC2 = (f2*)cC + (basePt >> 1);     // 1 f2 per pair

    const int chunksPerXcd = (P >> 6) >> 3;             // 192
    const int wavesPerXcd  = (gridDim.x >> 3) << 2;     // 32
    const int cpw  = chunksPerXcd / wavesPerXcd;        // 6
    const int xcd  = blockIdx.x & 7;
    const int wslot = ((blockIdx.x >> 3) << 2) + wave;  // 0..31
    const int c0 = xcd * chunksPerXcd + wslot * cpw;

    float A[21];
    float g[6];
#pragma unroll
    for (int i = 0; i < 21; ++i) A[i] = 0.f;
#pragma unroll
    for (int i = 0; i < 6; ++i) g[i] = 0.f;

    for (int c = c0; c < c0 + cpw; ++c) {
        const int pr = (c << 6) + lane;
        const f4 rv = ntload4(r4 + pr);
        const f4 wv = ntload4(w4 + pr);
        const f4 jd = ntload4(jd4 + pr);
        const f4* jp = jp4 + (size_t)pr * 6;
        const f4 q0 = ntload4(jp + 0);
        const f4 q1 = ntload4(jp + 1);
        const f4 q2 = ntload4(jp + 2);
        const f4 q3 = ntload4(jp + 3);
        const f4 q4 = ntload4(jp + 4);
        const f4 q5 = ntload4(jp + 5);

        float c7a[7], c7b[7];
        {
            const float ja[6] = {q0[0], q0[1], q0[2], q0[3], q1[0], q1[1]};
            const float jb[6] = {q1[2], q1[3], q2[0], q2[1], q2[2], q2[3]};
            accum_point(ja, jb, rv[0], rv[1], wv[0], wv[1], jd[0], jd[1],
                        lam, A, g, c7a);
        }
        {
            const float ja[6] = {q3[0], q3[1], q3[2], q3[3], q4[0], q4[1]};
            const float jb[6] = {q4[2], q4[3], q5[0], q5[1], q5[2], q5[3]};
            accum_point(ja, jb, rv[2], rv[3], wv[2], wv[3], jd[2], jd[3],
                        lam, A, g, c7b);
        }
        // tight-packed cache: 28 B/pt, unit-stride, write-back (keep in LLC)
        const size_t pt = (size_t)pr << 1;
        f4 a0 = {c7a[0], c7a[1], c7a[2], c7a[3]};
        f4 a1 = {c7b[0], c7b[1], c7b[2], c7b[3]};
        f4 bq = {c7a[4], c7a[5], c7b[4], c7b[5]};
        f2 cq = {c7a[6], c7b[6]};
        cA4[pt]     = a0;
        cA4[pt + 1] = a1;
        cB4[pr]     = bq;
        cC2[pr]     = cq;
    }

    float v[NACC];
#pragma unroll
    for (int i = 0; i < 21; ++i) v[i] = A[i];
#pragma unroll
    for (int i = 0; i < 6; ++i) v[21 + i] = g[i];
#pragma unroll
    for (int off = 32; off > 0; off >>= 1) {
#pragma unroll
        for (int i = 0; i < NACC; ++i) v[i] += __shfl_down(v[i], off, 64);
    }
    __shared__ float sred[4][NACC];
    if (lane == 0) {
#pragma unroll
        for (int i = 0; i < NACC; ++i) sred[wave][i] = v[i];
    }
    __syncthreads();
    if (threadIdx.x < NACC) {
        const float s = sred[0][threadIdx.x] + sred[1][threadIdx.x] +
                        sred[2][threadIdx.x] + sred[3][threadIdx.x];
        atomicAdd(&acc[b * 32 + threadIdx.x], s);
    }
}

__global__ void dba_solve(const float* __restrict__ acc,
                          const float* __restrict__ lmbda,
                          float* __restrict__ pose_out,
                          float* __restrict__ dp_ws, int B)
{
    const int b = blockIdx.x * blockDim.x + threadIdx.x;
    if (b >= B) return;
    solve6(acc + b * 32, lmbda[b], pose_out + b * 6, dp_ws + b * 6);
}

// ---------------- XCD-contiguous slim depth (exact shape) ------------------
// grid (128, B): 2048 blocks. Same XCD->contiguous-slab mapping; reads the
// 88 MB cache (mostly LLC-resident) + writes 12.6 MB nt.
__global__ __launch_bounds__(256) void dba_depth_swz(
    const float* __restrict__ cA, const float* __restrict__ cB,
    const float* __restrict__ cC, const float* __restrict__ dp_ws,
    float* __restrict__ depth_out, int N)
{
    const int b = blockIdx.y;
    float dp[6];
#pragma unroll
    for (int i = 0; i < 6; ++i) dp[i] = dp_ws[b * 6 + i];

    const size_t basePt = (size_t)b * (size_t)N;
    const int P = N >> 1;
    const f4* __restrict__ cA4 = (const f4*)cA + basePt;
    const f4* __restrict__ cB4 = (const f4*)cB + (basePt >> 1);
    const f2* __restrict__ cC2 = (const f2*)cC + (basePt >> 1);
    f2* __restrict__ out2 = (f2*)depth_out + (basePt >> 1);

    const int lane = threadIdx.x & 63;
    const int wave = threadIdx.x >> 6;
    const int pairsPerXcd   = P >> 3;                        // 12288
    const int pairsPerBlock = pairsPerXcd / (gridDim.x >> 3);// 768
    const int perWave = pairsPerBlock >> 2;                  // 192
    const int xcd = blockIdx.x & 7;
    const int base = xcd * pairsPerXcd + (blockIdx.x >> 3) * pairsPerBlock +
                     wave * perWave;

    for (int i = 0; i < perWave; i += 64) {
        const int pr = base + i + lane;
        const size_t pt = (size_t)pr << 1;
        const f4 a0 = cA4[pt];
        const f4 a1 = cA4[pt + 1];
        const f4 bq = cB4[pr];
        const f2 cq = cC2[pr];
        f2 o;
        o[0] = cq[0] - (a0[0] * dp[0] + a0[1] * dp[1] + a0[2] * dp[2] +
                        a0[3] * dp[3] + bq[0] * dp[4] + bq[1] * dp[5]);
        o[1] = cq[1] - (a1[0] * dp[0] + a1[1] * dp[1] + a1[2] * dp[2] +
                        a1[3] * dp[3] + bq[2] * dp[4] + bq[3] * dp[5]);
        __builtin_nontemporal_store(o, out2 + pr);
    }
}

// ---------------- generic fallback (any shape / small ws) ------------------
__global__ __launch_bounds__(256) void dba_reduce_fb(
    const float* __restrict__ r, const float* __restrict__ w,
    const float* __restrict__ J_p, const float* __restrict__ J_d,
    const float* __restrict__ lmbda, float* __restrict__ acc, int N)
{
    const int b = blockIdx.y;
    const float lam = lmbda[b];
    float A[21];
    float g[6];
#pragma unroll
    for (int i = 0; i < 21; ++i) A[i] = 0.f;
#pragma unroll
    for (int i = 0; i < 6; ++i) g[i] = 0.f;

    const size_t basePt = (size_t)b * (size_t)N;
    const int P = N >> 1;
    const f4* __restrict__ r4  = (const f4*)r   + (basePt >> 1);
    const f4* __restrict__ w4  = (const f4*)w   + (basePt >> 1);
    const f4* __restrict__ jd4 = (const f4*)J_d + (basePt >> 1);
    const f4* __restrict__ jp4 = (const f4*)J_p + basePt * 3;

    float c7a[7], c7b[7];
    for (int pr = blockIdx.x * blockDim.x + threadIdx.x; pr < P;
         pr += gridDim.x * blockDim.x) {
        const f4 rv = r4[pr];
        const f4 wv = w4[pr];
        const f4 jd = jd4[pr];
        const f4* jp = jp4 + (size_t)pr * 6;
        const f4 q0 = jp[0], q1 = jp[1], q2 = jp[2];
        const f4 q3 = jp[3], q4 = jp[4], q5 = jp[5];
        {
            const float ja[6] = {q0[0], q0[1], q0[2], q0[3], q1[0], q1[1]};
            const float jb[6] = {q1[2], q1[3], q2[0], q2[1], q2[2], q2[3]};
            accum_point(ja, jb, rv[0], rv[1], wv[0], wv[1], jd[0], jd[1],
                        lam, A, g, c7a);
        }
        {
            const float ja[6] = {q3[0], q3[1], q3[2], q3[3], q4[0], q4[1]};
            const float jb[6] = {q4[2], q4[3], q5[0], q5[1], q5[2], q5[3]};
            accum_point(ja, jb, rv[2], rv[3], wv[2], wv[3], jd[2], jd[3],
                        lam, A, g, c7b);
        }
    }

    float v[NACC];
#pragma unroll
    for (int i = 0; i < 21; ++i) v[i] = A[i];
#pragma unroll
    for (int i = 0; i < 6; ++i) v[21 + i] = g[i];
#pragma unroll
    for (int off = 32; off > 0; off >>= 1) {
#pragma unroll
        for (int i = 0; i < NACC; ++i) v[i] += __shfl_down(v[i], off, 64);
    }
    __shared__ float sred[4][NACC];
    const int wave = threadIdx.x >> 6;
    const int lane = threadIdx.x & 63;
    if (lane == 0) {
#pragma unroll
        for (int i = 0; i < NACC; ++i) sred[wave][i] = v[i];
    }
    __syncthreads();
    if (threadIdx.x < NACC) {
        const float s = sred[0][threadIdx.x] + sred[1][threadIdx.x] +
                        sred[2][threadIdx.x] + sred[3][threadIdx.x];
        atomicAdd(&acc[b * 32 + threadIdx.x], s);
    }
}

__global__ __launch_bounds__(256) void dba_depth_fb(
    const float* __restrict__ r, const float* __restrict__ w,
    const float* __restrict__ J_p, const float* __restrict__ J_d,
    const float* __restrict__ lmbda, const float* __restrict__ dp_ws,
    float* __restrict__ depth_out, int N)
{
    const int b = blockIdx.y;
    const float lam = lmbda[b];
    float dp[6];
#pragma unroll
    for (int i = 0; i < 6; ++i) dp[i] = dp_ws[b * 6 + i];

    const size_t basePt = (size_t)b * (size_t)N;
    const int P = N >> 1;
    const f4* __restrict__ r4  = (const f4*)r   + (basePt >> 1);
    const f4* __restrict__ w4  = (const f4*)w   + (basePt >> 1);
    const f4* __restrict__ jd4 = (const f4*)J_d + (basePt >> 1);
    const f4* __restrict__ jp4 = (const f4*)J_p + basePt * 3;
    f2* __restrict__ out2 = (f2*)depth_out + (basePt >> 1);

    for (int pr = blockIdx.x * blockDim.x + threadIdx.x; pr < P;
         pr += gridDim.x * blockDim.x) {
        const f4 rv = r4[pr];
        const f4 wv = w4[pr];
        const f4 jd = jd4[pr];
        const f4* jp = jp4 + (size_t)pr * 6;
        const f4 q0 = jp[0], q1 = jp[1], q2 = jp[2];
        const f4 q3 = jp[3], q4 = jp[4], q5 = jp[5];
        f2 o;
        {
            const float ja[6] = {q0[0], q0[1], q0[2], q0[3], q1[0], q1[1]};
            const float jb[6] = {q1[2], q1[3], q2[0], q2[1], q2[2], q2[3]};
            float v = 0.f;
#pragma unroll
            for (int i = 0; i < 6; ++i)
                v += (ja[i] * jd[0] + jb[i] * jd[1]) * dp[i];
            v *= wv[0];
            const float hdd = wv[0] * (jd[0] * jd[0] + jd[1] * jd[1]);
            const float inv = 1.0f / fmaxf(hdd + lam + wv[1], 1e-4f);
            const float gd  = wv[0] * (jd[0] * rv[0] + jd[1] * rv[1]);
            o[0] = inv * (gd - v);
        }
        {
            const float ja[6] = {q3[0], q3[1], q3[2], q3[3], q4[0], q4[1]};
            const float jb[6] = {q4[2], q4[3], q5[0], q5[1], q5[2], q5[3]};
            float v = 0.f;
#pragma unroll
            for (int i = 0; i < 6; ++i)
                v += (ja[i] * jd[2] + jb[i] * jd[3]) * dp[i];
            v *= wv[2];
            const float hdd = wv[2] * (jd[2] * jd[2] + jd[3] * jd[3]);
            const float inv = 1.0f / fmaxf(hdd + lam + wv[3], 1e-4f);
            const float gd  = wv[2] * (jd[2] * rv[2] + jd[3] * rv[3]);
            o[1] = inv * (gd - v);
        }
        out2[pr] = o;
    }
}

extern "C" void kernel_launch(void* const* d_in, const int* in_sizes, int n_in,
                              void* d_out, int out_size, void* d_ws, size_t ws_size,
                              hipStream_t stream)
{
    const float* r   = (const float*)d_in[0];
    const float* w   = (const float*)d_in[1];
    const float* J_p = (const float*)d_in[2];
    const float* J_d = (const float*)d_in[3];
    const float* lmb = (const float*)d_in[4];
    const int B = in_sizes[4];            // 16
    const int N = in_sizes[0] / (B * 2);  // 196608

    // ws layout (floats): acc[512] @0, dp[?] @512, cache arrays @1024
    float* acc   = (float*)d_ws;
    float* dp_ws = (float*)d_ws + 512;
    float* cA    = (float*)d_ws + 1024;                 // 4 floats/pt
    float* cB    = cA + (size_t)B * N * 4;              // 2 floats/pt
    float* cC    = cB + (size_t)B * N * 2;              // 1 float/pt
    float* out   = (float*)d_out;
    float* pose  = out;
    float* depth = out + B * 6;

    const size_t cacheBytes = (size_t)B * (size_t)N * 28;
    const bool fast = (B == 16) && (N == 196608) &&
                      (ws_size >= 4096 + cacheBytes);

    hipMemsetAsync(acc, 0, B * 32 * sizeof(float), stream);

    if (fast) {
        dim3 rgrid(64, B);    // 1024 blocks = 4/CU, XCD-contiguous slabs
        dba_reduce_swz<<<rgrid, 256, 0, stream>>>(r, w, J_p, J_d, lmb, acc,
                                                  cA, cB, cC, N);
        dba_solve<<<1, 64, 0, stream>>>(acc, lmb, pose, dp_ws, B);
        dim3 dgrid(128, B);   // 2048 blocks, XCD-contiguous slabs
        dba_depth_swz<<<dgrid, 256, 0, stream>>>(cA, cB, cC, dp_ws, depth, N);
    } else {
        dim3 grid(192, B);
        dba_reduce_fb<<<grid, 256, 0, stream>>>(r, w, J_p, J_d, lmb, acc, N);
        dba_solve<<<1, 64, 0, stream>>>(acc, lmb, pose, dp_ws, B);
        dba_depth_fb<<<grid, 256, 0, stream>>>(r, w, J_p, J_d, lmb, dp_ws,
                                               depth, N);
    }
}

// Round 8
// 305.970 us; speedup vs baseline: 2.0209x; 1.0202x over previous
//
#include <hip/hip_runtime.h>

// DBASolver: B=16, N=196608, C=2.
// Structure: reduce(+28B/pt c7 cache) -> 16x 6x6 solve -> slim depth.
// Evidence R1-R8: delivered read rate pinned at 2.46 TB/s across coalescing
// (R2 null), nt (R4/R8 null), XCD-contiguous (R8 null), occupancy 10-48 w/CU.
// BUT: VGPR_Count was 64 in EVERY round -> compiler physically could not
// keep >2-3 f4 loads in flight (27 acc + 36 load regs > 64). R4's prefetch
// was silently deleted for the same reason (no waves hint in launch_bounds).
// m146 RMSNorm hits 4.89 TB/s read on this chip => the read path CAN go 2x.
// R9: __launch_bounds__(256,2) => 128-VGPR budget; explicit 2-deep rotate
// (18 f4 loads in flight); plain input loads (LLC allocation back; nt only
// on final output store). VERIFY: VGPR_Count must read ~110-128.

using f4 = __attribute__((ext_vector_type(4))) float;
using f2 = __attribute__((ext_vector_type(2))) float;

constexpr int NACC = 27;  // 21 upper-tri H + 6 g

// Per-point contribution; exports c7 = {hii[0..5], gdinv}:
// depth = gdinv - hii.dp (identical arithmetic to what pass 3 needs).
__device__ __forceinline__ void accum_point(
    const float ja[6], const float jb[6],
    float r0, float r1, float conf, float nlam, float jd0, float jd1,
    float lam, float* __restrict__ A, float* __restrict__ g,
    float* __restrict__ c7)
{
    float h[6], gp[6];
#pragma unroll
    for (int i = 0; i < 6; ++i) {
        h[i]  = conf * (ja[i] * jd0 + jb[i] * jd1);   // H_pd[b,n,i]
        gp[i] = conf * (ja[i] * r0 + jb[i] * r1);     // g_p contribution
    }
    const float hdd = conf * (jd0 * jd0 + jd1 * jd1);
    const float inv = 1.0f / fmaxf(hdd + lam + nlam, 1e-4f);
    const float gd  = conf * (jd0 * r0 + jd1 * r1);
    const float gdinv = gd * inv;
    c7[6] = gdinv;
    int idx = 0;
#pragma unroll
    for (int i = 0; i < 6; ++i) {
        const float hii = h[i] * inv;
        c7[i] = hii;
#pragma unroll
        for (int j = i; j < 6; ++j) {
            A[idx] += conf * (ja[i] * ja[j] + jb[i] * jb[j]) - hii * h[j];
            ++idx;
        }
        g[i] += gp[i] - h[i] * gdinv;
    }
}

__device__ __forceinline__ void solve6(const float* __restrict__ a, float lam,
                                       float* __restrict__ pose,
                                       float* __restrict__ dp)
{
    float M[6][7];
    int idx = 0;
#pragma unroll
    for (int i = 0; i < 6; ++i) {
#pragma unroll
        for (int j = i; j < 6; ++j) {
            const float t = a[idx++];
            M[i][j] = t;
            M[j][i] = t;
        }
    }
#pragma unroll
    for (int i = 0; i < 6; ++i) M[i][6] = a[21 + i];
#pragma unroll
    for (int i = 0; i < 6; ++i) M[i][i] += lam + 0.011f;
    // Gauss-Jordan, no pivoting (strongly diagonally dominant SPD)
#pragma unroll
    for (int k = 0; k < 6; ++k) {
        const float piv = 1.0f / M[k][k];
#pragma unroll
        for (int j = 0; j < 7; ++j) M[k][j] *= piv;
#pragma unroll
        for (int i = 0; i < 6; ++i) {
            if (i == k) continue;
            const float f = M[i][k];
#pragma unroll
            for (int j = 0; j < 7; ++j) M[i][j] -= f * M[k][j];
        }
    }
#pragma unroll
    for (int i = 0; i < 6; ++i) {
        const float x = M[i][6];
        dp[i] = x;                                   // UNCLIPPED for depth
        pose[i] = fminf(fmaxf(x, -2.0f), 2.0f);
    }
}

// ---------------- deep-ILP reduce (exact shape) ----------------------------
// grid (128, B) = 2048 blocks. XCD-contiguous slabs: XCD k owns chunks
// [k*192,(k+1)*192); 16 blocks x 4 waves per XCD take 3 contiguous chunks
// each. 2-deep software pipeline: 18 f4 loads in flight per wave.
__global__ __launch_bounds__(256, 2) void dba_reduce_swz(
    const float* __restrict__ r, const float* __restrict__ w,
    const float* __restrict__ J_p, const float* __restrict__ J_d,
    const float* __restrict__ lmbda, float* __restrict__ acc,
    float* __restrict__ cA, float* __restrict__ cB, float* __restrict__ cC,
    int N)
{
    const int b = blockIdx.y;
    const float lam = lmbda[b];
    const int lane = threadIdx.x & 63;
    const int wave = threadIdx.x >> 6;

    const size_t basePt = (size_t)b * (size_t)N;
    const int P = N >> 1;
    const f4* __restrict__ r4  = (const f4*)r   + (basePt >> 1);
    const f4* __restrict__ w4  = (const f4*)w   + (basePt >> 1);
    const f4* __restrict__ jd4 = (const f4*)J_d + (basePt >> 1);
    const f4* __restrict__ jp4 = (const f4*)J_p + basePt * 3;
    f4* __restrict__ cA4 = (f4*)cA + basePt;            // 1 f4 per point
    f4* __restrict__ cB4 = (f4*)cB + (basePt >> 1);     // 1 f4 per pair
    f2* __restrict__ cC2 = (f2*)cC + (basePt >> 1);     // 1 f2 per pair

    const int chunksPerXcd = (P >> 6) >> 3;             // 192
    const int wavesPerXcd  = (gridDim.x >> 3) << 2;     // 64
    const int cpw  = chunksPerXcd / wavesPerXcd;        // 3
    const int xcd  = blockIdx.x & 7;
    const int wslot = ((blockIdx.x >> 3) << 2) + wave;  // 0..63
    const int c0 = xcd * chunksPerXcd + wslot * cpw;

    float A[21];
    float g[6];
#pragma unroll
    for (int i = 0; i < 21; ++i) A[i] = 0.f;
#pragma unroll
    for (int i = 0; i < 6; ++i) g[i] = 0.f;

    // ---- 2-deep pipeline: issue chunk i+1's 9 loads before consuming i ----
    int c = c0;
    int pr = (c << 6) + lane;
    f4 c_rv = r4[pr];
    f4 c_wv = w4[pr];
    f4 c_jd = jd4[pr];
    const f4* jpc = jp4 + (size_t)pr * 6;
    f4 c_q0 = jpc[0];
    f4 c_q1 = jpc[1];
    f4 c_q2 = jpc[2];
    f4 c_q3 = jpc[3];
    f4 c_q4 = jpc[4];
    f4 c_q5 = jpc[5];

    for (int i = 0; i < cpw; ++i) {
        const int cn  = (i + 1 < cpw) ? c + 1 : c;   // clamp on last iter
        const int prn = (cn << 6) + lane;
        f4 n_rv = r4[prn];
        f4 n_wv = w4[prn];
        f4 n_jd = jd4[prn];
        const f4* jpn = jp4 + (size_t)prn * 6;
        f4 n_q0 = jpn[0];
        f4 n_q1 = jpn[1];
        f4 n_q2 = jpn[2];
        f4 n_q3 = jpn[3];
        f4 n_q4 = jpn[4];
        f4 n_q5 = jpn[5];

        float c7a[7], c7b[7];
        {
            const float ja[6] = {c_q0[0], c_q0[1], c_q0[2], c_q0[3], c_q1[0], c_q1[1]};
            const float jb[6] = {c_q1[2], c_q1[3], c_q2[0], c_q2[1], c_q2[2], c_q2[3]};
            accum_point(ja, jb, c_rv[0], c_rv[1], c_wv[0], c_wv[1],
                        c_jd[0], c_jd[1], lam, A, g, c7a);
        }
        {
            const float ja[6] = {c_q3[0], c_q3[1], c_q3[2], c_q3[3], c_q4[0], c_q4[1]};
            const float jb[6] = {c_q4[2], c_q4[3], c_q5[0], c_q5[1], c_q5[2], c_q5[3]};
            accum_point(ja, jb, c_rv[2], c_rv[3], c_wv[2], c_wv[3],
                        c_jd[2], c_jd[3], lam, A, g, c7b);
        }
        // tight-packed cache: 28 B/pt, unit-stride, write-back (LLC retain)
        {
            const size_t pt = (size_t)pr << 1;
            f4 a0 = {c7a[0], c7a[1], c7a[2], c7a[3]};
            f4 a1 = {c7b[0], c7b[1], c7b[2], c7b[3]};
            f4 bq = {c7a[4], c7a[5], c7b[4], c7b[5]};
            f2 cq = {c7a[6], c7b[6]};
            cA4[pt]     = a0;
            cA4[pt + 1] = a1;
            cB4[pr]     = bq;
            cC2[pr]     = cq;
        }

        // rotate prefetched registers in
        c_rv = n_rv; c_wv = n_wv; c_jd = n_jd;
        c_q0 = n_q0; c_q1 = n_q1; c_q2 = n_q2;
        c_q3 = n_q3; c_q4 = n_q4; c_q5 = n_q5;
        c = cn; pr = prn;
    }

    float v[NACC];
#pragma unroll
    for (int i = 0; i < 21; ++i) v[i] = A[i];
#pragma unroll
    for (int i = 0; i < 6; ++i) v[21 + i] = g[i];
#pragma unroll
    for (int off = 32; off > 0; off >>= 1) {
#pragma unroll
        for (int i = 0; i < NACC; ++i) v[i] += __shfl_down(v[i], off, 64);
    }
    __shared__ float sred[4][NACC];
    if (lane == 0) {
#pragma unroll
        for (int i = 0; i < NACC; ++i) sred[wave][i] = v[i];
    }
    __syncthreads();
    if (threadIdx.x < NACC) {
        const float s = sred[0][threadIdx.x] + sred[1][threadIdx.x] +
                        sred[2][threadIdx.x] + sred[3][threadIdx.x];
        atomicAdd(&acc[b * 32 + threadIdx.x], s);
    }
}

__global__ void dba_solve(const float* __restrict__ acc,
                          const float* __restrict__ lmbda,
                          float* __restrict__ pose_out,
                          float* __restrict__ dp_ws, int B)
{
    const int b = blockIdx.x * blockDim.x + threadIdx.x;
    if (b >= B) return;
    solve6(acc + b * 32, lmbda[b], pose_out + b * 6, dp_ws + b * 6);
}

// ---------------- slim depth with 2-deep pipeline (exact shape) ------------
__global__ __launch_bounds__(256) void dba_depth_swz(
    const float* __restrict__ cA, const float* __restrict__ cB,
    const float* __restrict__ cC, const float* __restrict__ dp_ws,
    float* __restrict__ depth_out, int N)
{
    const int b = blockIdx.y;
    float dp[6];
#pragma unroll
    for (int i = 0; i < 6; ++i) dp[i] = dp_ws[b * 6 + i];

    const size_t basePt = (size_t)b * (size_t)N;
    const int P = N >> 1;
    const f4* __restrict__ cA4 = (const f4*)cA + basePt;
    const f4* __restrict__ cB4 = (const f4*)cB + (basePt >> 1);
    const f2* __restrict__ cC2 = (const f2*)cC + (basePt >> 1);
    f2* __restrict__ out2 = (f2*)depth_out + (basePt >> 1);

    const int lane = threadIdx.x & 63;
    const int wave = threadIdx.x >> 6;
    const int pairsPerXcd   = P >> 3;                        // 12288
    const int pairsPerBlock = pairsPerXcd / (gridDim.x >> 3);// 768 @128
    const int perWave = pairsPerBlock >> 2;                  // 192
    const int iters = perWave >> 6;                          // 3
    const int xcd = blockIdx.x & 7;
    const int base = xcd * pairsPerXcd + (blockIdx.x >> 3) * pairsPerBlock +
                     wave * perWave;

    int pr = base + lane;
    f4 a0 = cA4[(size_t)pr << 1];
    f4 a1 = cA4[((size_t)pr << 1) + 1];
    f4 bq = cB4[pr];
    f2 cq = cC2[pr];

    for (int i = 0; i < iters; ++i) {
        const int prn = (i + 1 < iters) ? pr + 64 : pr;
        f4 na0 = cA4[(size_t)prn << 1];
        f4 na1 = cA4[((size_t)prn << 1) + 1];
        f4 nbq = cB4[prn];
        f2 ncq = cC2[prn];

        f2 o;
        o[0] = cq[0] - (a0[0] * dp[0] + a0[1] * dp[1] + a0[2] * dp[2] +
                        a0[3] * dp[3] + bq[0] * dp[4] + bq[1] * dp[5]);
        o[1] = cq[1] - (a1[0] * dp[0] + a1[1] * dp[1] + a1[2] * dp[2] +
                        a1[3] * dp[3] + bq[2] * dp[4] + bq[3] * dp[5]);
        __builtin_nontemporal_store(o, out2 + pr);

        a0 = na0; a1 = na1; bq = nbq; cq = ncq;
        pr = prn;
    }
}

// ---------------- generic fallback (any shape / small ws) ------------------
__global__ __launch_bounds__(256) void dba_reduce_fb(
    const float* __restrict__ r, const float* __restrict__ w,
    const float* __restrict__ J_p, const float* __restrict__ J_d,
    const float* __restrict__ lmbda, float* __restrict__ acc, int N)
{
    const int b = blockIdx.y;
    const float lam = lmbda[b];
    float A[21];
    float g[6];
#pragma unroll
    for (int i = 0; i < 21; ++i) A[i] = 0.f;
#pragma unroll
    for (int i = 0; i < 6; ++i) g[i] = 0.f;

    const size_t basePt = (size_t)b * (size_t)N;
    const int P = N >> 1;
    const f4* __restrict__ r4  = (const f4*)r   + (basePt >> 1);
    const f4* __restrict__ w4  = (const f4*)w   + (basePt >> 1);
    const f4* __restrict__ jd4 = (const f4*)J_d + (basePt >> 1);
    const f4* __restrict__ jp4 = (const f4*)J_p + basePt * 3;

    float c7a[7], c7b[7];
    for (int pr = blockIdx.x * blockDim.x + threadIdx.x; pr < P;
         pr += gridDim.x * blockDim.x) {
        const f4 rv = r4[pr];
        const f4 wv = w4[pr];
        const f4 jd = jd4[pr];
        const f4* jp = jp4 + (size_t)pr * 6;
        const f4 q0 = jp[0], q1 = jp[1], q2 = jp[2];
        const f4 q3 = jp[3], q4 = jp[4], q5 = jp[5];
        {
            const float ja[6] = {q0[0], q0[1], q0[2], q0[3], q1[0], q1[1]};
            const float jb[6] = {q1[2], q1[3], q2[0], q2[1], q2[2], q2[3]};
            accum_point(ja, jb, rv[0], rv[1], wv[0], wv[1], jd[0], jd[1],
                        lam, A, g, c7a);
        }
        {
            const float ja[6] = {q3[0], q3[1], q3[2], q3[3], q4[0], q4[1]};
            const float jb[6] = {q4[2], q4[3], q5[0], q5[1], q5[2], q5[3]};
            accum_point(ja, jb, rv[2], rv[3], wv[2], wv[3], jd[2], jd[3],
                        lam, A, g, c7b);
        }
    }

    float v[NACC];
#pragma unroll
    for (int i = 0; i < 21; ++i) v[i] = A[i];
#pragma unroll
    for (int i = 0; i < 6; ++i) v[21 + i] = g[i];
#pragma unroll
    for (int off = 32; off > 0; off >>= 1) {
#pragma unroll
        for (int i = 0; i < NACC; ++i) v[i] += __shfl_down(v[i], off, 64);
    }
    __shared__ float sred[4][NACC];
    const int wave = threadIdx.x >> 6;
    const int lane = threadIdx.x & 63;
    if (lane == 0) {
#pragma unroll
        for (int i = 0; i < NACC; ++i) sred[wave][i] = v[i];
    }
    __syncthreads();
    if (threadIdx.x < NACC) {
        const float s = sred[0][threadIdx.x] + sred[1][threadIdx.x] +
                        sred[2][threadIdx.x] + sred[3][threadIdx.x];
        atomicAdd(&acc[b * 32 + threadIdx.x], s);
    }
}

__global__ __launch_bounds__(256) void dba_depth_fb(
    const float* __restrict__ r, const float* __restrict__ w,
    const float* __restrict__ J_p, const float* __restrict__ J_d,
    const float* __restrict__ lmbda, const float* __restrict__ dp_ws,
    float* __restrict__ depth_out, int N)
{
    const int b = blockIdx.y;
    const float lam = lmbda[b];
    float dp[6];
#pragma unroll
    for (int i = 0; i < 6; ++i) dp[i] = dp_ws[b * 6 + i];

    const size_t basePt = (size_t)b * (size_t)N;
    const int P = N >> 1;
    const f4* __restrict__ r4  = (const f4*)r   + (basePt >> 1);
    const f4* __restrict__ w4  = (const f4*)w   + (basePt >> 1);
    const f4* __restrict__ jd4 = (const f4*)J_d + (basePt >> 1);
    const f4* __restrict__ jp4 = (const f4*)J_p + basePt * 3;
    f2* __restrict__ out2 = (f2*)depth_out + (basePt >> 1);

    for (int pr = blockIdx.x * blockDim.x + threadIdx.x; pr < P;
         pr += gridDim.x * blockDim.x) {
        const f4 rv = r4[pr];
        const f4 wv = w4[pr];
        const f4 jd = jd4[pr];
        const f4* jp = jp4 + (size_t)pr * 6;
        const f4 q0 = jp[0], q1 = jp[1], q2 = jp[2];
        const f4 q3 = jp[3], q4 = jp[4], q5 = jp[5];
        f2 o;
        {
            const float ja[6] = {q0[0], q0[1], q0[2], q0[3], q1[0], q1[1]};
            const float jb[6] = {q1[2], q1[3], q2[0], q2[1], q2[2], q2[3]};
            float v = 0.f;
#pragma unroll
            for (int i = 0; i < 6; ++i)
                v += (ja[i] * jd[0] + jb[i] * jd[1]) * dp[i];
            v *= wv[0];
            const float hdd = wv[0] * (jd[0] * jd[0] + jd[1] * jd[1]);
            const float inv = 1.0f / fmaxf(hdd + lam + wv[1], 1e-4f);
            const float gd  = wv[0] * (jd[0] * rv[0] + jd[1] * rv[1]);
            o[0] = inv * (gd - v);
        }
        {
            const float ja[6] = {q3[0], q3[1], q3[2], q3[3], q4[0], q4[1]};
            const float jb[6] = {q4[2], q4[3], q5[0], q5[1], q5[2], q5[3]};
            float v = 0.f;
#pragma unroll
            for (int i = 0; i < 6; ++i)
                v += (ja[i] * jd[2] + jb[i] * jd[3]) * dp[i];
            v *= wv[2];
            const float hdd = wv[2] * (jd[2] * jd[2] + jd[3] * jd[3]);
            const float inv = 1.0f / fmaxf(hdd + lam + wv[3], 1e-4f);
            const float gd  = wv[2] * (jd[2] * rv[2] + jd[3] * rv[3]);
            o[1] = inv * (gd - v);
        }
        out2[pr] = o;
    }
}

extern "C" void kernel_launch(void* const* d_in, const int* in_sizes, int n_in,
                              void* d_out, int out_size, void* d_ws, size_t ws_size,
                              hipStream_t stream)
{
    const float* r   = (const float*)d_in[0];
    const float* w   = (const float*)d_in[1];
    const float* J_p = (const float*)d_in[2];
    const float* J_d = (const float*)d_in[3];
    const float* lmb = (const float*)d_in[4];
    const int B = in_sizes[4];            // 16
    const int N = in_sizes[0] / (B * 2);  // 196608

    // ws layout (floats): acc[512] @0, dp @512, cache arrays @1024
    float* acc   = (float*)d_ws;
    float* dp_ws = (float*)d_ws + 512;
    float* cA    = (float*)d_ws + 1024;                 // 4 floats/pt
    float* cB    = cA + (size_t)B * N * 4;              // 2 floats/pt
    float* cC    = cB + (size_t)B * N * 2;              // 1 float/pt
    float* out   = (float*)d_out;
    float* pose  = out;
    float* depth = out + B * 6;

    const size_t cacheBytes = (size_t)B * (size_t)N * 28;
    const bool fast = (B == 16) && (N == 196608) &&
                      (ws_size >= 4096 + cacheBytes);

    hipMemsetAsync(acc, 0, B * 32 * sizeof(float), stream);

    if (fast) {
        dim3 rgrid(128, B);   // 2048 blocks, XCD-contiguous, 3 chunks/wave
        dba_reduce_swz<<<rgrid, 256, 0, stream>>>(r, w, J_p, J_d, lmb, acc,
                                                  cA, cB, cC, N);
        dba_solve<<<1, 64, 0, stream>>>(acc, lmb, pose, dp_ws, B);
        dim3 dgrid(128, B);   // 2048 blocks, XCD-contiguous slabs
        dba_depth_swz<<<dgrid, 256, 0, stream>>>(cA, cB, cC, dp_ws, depth, N);
    } else {
        dim3 grid(192, B);
        dba_reduce_fb<<<grid, 256, 0, stream>>>(r, w, J_p, J_d, lmb, acc, N);
        dba_solve<<<1, 64, 0, stream>>>(acc, lmb, pose, dp_ws, B);
        dba_depth_fb<<<grid, 256, 0, stream>>>(r, w, J_p, J_d, lmb, dp_ws,
                                               depth, N);
    }
}